// Round 6
// baseline (461.311 us; speedup 1.0000x reference)
//
#include <hip/hip_runtime.h>
#include <stdint.h>

typedef __bf16 bf16x8 __attribute__((ext_vector_type(8)));
typedef float f32x4 __attribute__((ext_vector_type(4)));
typedef unsigned short u16x8 __attribute__((ext_vector_type(8)));
typedef unsigned int u32x4 __attribute__((ext_vector_type(4)));

__device__ __forceinline__ unsigned short f2bf(float f) {
    unsigned int u = __builtin_bit_cast(unsigned int, f);
    unsigned int r = u + 0x7fffu + ((u >> 16) & 1u);
    return (unsigned short)(r >> 16);
}

// v_cvt_pk_bf16_f32: lo <- bf16(a), hi <- bf16(b)
__device__ __forceinline__ unsigned int cvt_pk_bf16(float a, float b) {
    unsigned int r;
    asm("v_cvt_pk_bf16_f32 %0, %1, %2" : "=v"(r) : "v"(a), "v"(b));
    return r;
}

// async global->LDS, 16B per lane. LDS dest = wave-uniform base + lane*16.
__device__ __forceinline__ void async16(const void* g, void* l) {
    __builtin_amdgcn_global_load_lds(
        (const __attribute__((address_space(1))) void*)g,
        (__attribute__((address_space(3))) void*)l, 16, 0, 0);
}

// ---------------------------------------------------------------------------
// x fp32 -> bf16, elementwise (8 elems/thread)
// ---------------------------------------------------------------------------
__global__ __launch_bounds__(256) void cast_bf16(
    const float* __restrict__ src, unsigned short* __restrict__ dst, int n8)
{
    int i = blockIdx.x * 256 + threadIdx.x;
    if (i >= n8) return;
    const float* f = src + (size_t)i * 8;
    f32x4 a = *reinterpret_cast<const f32x4*>(f);
    f32x4 b = *reinterpret_cast<const f32x4*>(f + 4);
    u16x8 r;
    r[0]=f2bf(a[0]); r[1]=f2bf(a[1]); r[2]=f2bf(a[2]); r[3]=f2bf(a[3]);
    r[4]=f2bf(b[0]); r[5]=f2bf(b[1]); r[6]=f2bf(b[2]); r[7]=f2bf(b[3]);
    *reinterpret_cast<u16x8*>(dst + (size_t)i * 8) = r;
}

// ---------------------------------------------------------------------------
// W fp32 [R][Cc] -> bf16 W^T [Cc][R]. 64x64 tiles, XOR-swizzled LDS
// ---------------------------------------------------------------------------
__global__ __launch_bounds__(256) void transpose_cast_f32(
    const float* __restrict__ src, unsigned short* __restrict__ dst, int R, int Cc)
{
    __shared__ unsigned short St[64 * 64];
    const int tid = threadIdx.x;
    const int r0 = blockIdx.y * 64, c0 = blockIdx.x * 64;
    const int lr  = tid >> 2;          // 0..63
    const int lcb = (tid & 3) * 16;    // 0,16,32,48
    const float* sp = src + (size_t)(r0 + lr) * Cc + c0 + lcb;
    #pragma unroll
    for (int u = 0; u < 4; u++) {
        f32x4 v = *reinterpret_cast<const f32x4*>(sp + 4 * u);
        #pragma unroll
        for (int e = 0; e < 4; e++) {
            int c = lcb + 4 * u + e;
            St[c * 64 + (((lr >> 3) ^ ((c >> 4) & 3)) << 3) + (lr & 7)] = f2bf(v[e]);
        }
    }
    __syncthreads();
    #pragma unroll
    for (int i = 0; i < 2; i++) {
        int ck = tid + 256 * i;
        int c = ck >> 3, ch = ck & 7;
        u16x8 val = *reinterpret_cast<const u16x8*>(&St[c * 64 + ((ch ^ ((c >> 4) & 3)) << 3)]);
        *reinterpret_cast<u16x8*>(dst + (size_t)(c0 + c) * R + r0 + ch * 8) = val;
    }
}

// ---------------------------------------------------------------------------
// V-part of qkv -> VT [b][h][d][t'] with per-32 t-permutation matching the
// swapped-QK^T P layout (see flash_attn).
// ---------------------------------------------------------------------------
__global__ __launch_bounds__(256) void vtrans(
    const unsigned short* __restrict__ qkv, unsigned short* __restrict__ VT)
{
    const int T = 2048, CH = 6144;
    __shared__ unsigned short St[64 * 64];
    const int tid = threadIdx.x;
    const int bh = blockIdx.z;
    const int b = bh >> 4, h = bh & 15;
    const int t0 = blockIdx.x * 64, d0 = blockIdx.y * 64;
    const int lr  = tid >> 2;
    const int lcb = (tid & 3) * 16;
    const unsigned short* sp = qkv + (size_t)(b * T + t0 + lr) * CH + 4096 + h * 128 + d0 + lcb;
    u16x8 v0 = *reinterpret_cast<const u16x8*>(sp);
    u16x8 v1 = *reinterpret_cast<const u16x8*>(sp + 8);
    #pragma unroll
    for (int e = 0; e < 8; e++) {
        int c = lcb + e;
        St[c * 64 + (((lr >> 3) ^ ((c >> 4) & 3)) << 3) + (lr & 7)] = v0[e];
        c = lcb + 8 + e;
        St[c * 64 + (((lr >> 3) ^ ((c >> 4) & 3)) << 3) + (lr & 7)] = v1[e];
    }
    __syncthreads();
    #pragma unroll
    for (int i = 0; i < 2; i++) {
        int ck = tid + 256 * i;
        int d = ck >> 3, ch = ck & 7;
        const int Q = ch & 3, B32 = ch >> 2;
        u16x8 val;
        #pragma unroll
        for (int e = 0; e < 4; e++) {
            int ta = 32 * B32 + 4 * Q + e;        // first half of chunk
            int tb = ta + 16;                     // second half
            val[e]     = St[d * 64 + (((ta >> 3) ^ ((d >> 4) & 3)) << 3) + (ta & 7)];
            val[4 + e] = St[d * 64 + (((tb >> 3) ^ ((d >> 4) & 3)) << 3) + (tb & 7)];
        }
        *reinterpret_cast<u16x8*>(VT + (size_t)(bh * 128 + d0 + d) * T + t0 + ch * 8) = val;
    }
}

// ---------------------------------------------------------------------------
// 128x128 double-buffered GEMM, single-barrier counted pipeline + T2 swizzle
// (rounds 4+5, proven). Kept for GEMM2 (512 blocks -> good shaping).
// ---------------------------------------------------------------------------
__global__ __launch_bounds__(256) void gemm_bt(
    const unsigned short* __restrict__ A,   // [M][K] bf16
    const unsigned short* __restrict__ BT,  // [N][K] bf16
    void* __restrict__ C, int M, int N, int K, int cF32)
{
    __shared__ unsigned short As[2][128 * 32];
    __shared__ unsigned short Bs[2][128 * 32];
    const int tid = threadIdx.x;
    const int w = tid >> 6, lane = tid & 63;
    const int quad = lane >> 4, l16 = lane & 15;
    const int wm = (w >> 1) * 64, wn = (w & 1) * 64;
    const int m0 = blockIdx.y * 128, n0 = blockIdx.x * 128;

    const int srow = w * 16 + (lane >> 2);
    const int scol = ((lane & 3) ^ ((lane >> 3) & 3)) * 8;   // inverse-swizzled source chunk
    const unsigned short* aG = A  + (size_t)(m0 + srow) * K + scol;
    const unsigned short* bG = BT + (size_t)(n0 + srow) * K + scol;
    const int ldsO = (w * 16) * 32;            // wave-uniform LDS offset

    const int kch = (quad ^ ((l16 >> 1) & 3)) * 8;   // swizzled fragment chunk

    f32x4 acc[4][4] = {};
    const int nkt = K >> 5;

    async16(aG, &As[0][ldsO]);
    async16(aG + (size_t)64 * K, &As[0][ldsO + 64 * 32]);
    async16(bG, &Bs[0][ldsO]);
    async16(bG + (size_t)64 * K, &Bs[0][ldsO + 64 * 32]);
    asm volatile("s_waitcnt vmcnt(0)\n\ts_barrier" ::: "memory");

    int ct = 0;
    for (int t = 0; t < nkt; ++t) {
        if (t + 1 < nkt) {
            const int k1 = (t + 1) * 32;
            async16(aG + k1, &As[ct ^ 1][ldsO]);
            async16(aG + (size_t)64 * K + k1, &As[ct ^ 1][ldsO + 64 * 32]);
            async16(bG + k1, &Bs[ct ^ 1][ldsO]);
            async16(bG + (size_t)64 * K + k1, &Bs[ct ^ 1][ldsO + 64 * 32]);
        }

        bf16x8 af[4], bf[4];
        #pragma unroll
        for (int i = 0; i < 4; i++)
            af[i] = *reinterpret_cast<const bf16x8*>(&As[ct][(wm + i * 16 + l16) * 32 + kch]);
        #pragma unroll
        for (int c = 0; c < 4; c++)
            bf[c] = *reinterpret_cast<const bf16x8*>(&Bs[ct][(wn + c * 16 + l16) * 32 + kch]);

        __builtin_amdgcn_s_setprio(1);
        #pragma unroll
        for (int i = 0; i < 4; i++)
            #pragma unroll
            for (int c = 0; c < 4; c++)
                acc[i][c] = __builtin_amdgcn_mfma_f32_16x16x32_bf16(af[i], bf[c], acc[i][c], 0, 0, 0);
        __builtin_amdgcn_s_setprio(0);

        asm volatile("s_waitcnt vmcnt(0) lgkmcnt(0)\n\ts_barrier" ::: "memory");
        ct ^= 1;
    }

    #pragma unroll
    for (int i = 0; i < 4; i++)
        #pragma unroll
        for (int c = 0; c < 4; c++)
            #pragma unroll
            for (int r = 0; r < 4; r++) {
                const int row = m0 + wm + i * 16 + quad * 4 + r;
                const int col = n0 + wn + c * 16 + l16;
                const size_t off = (size_t)row * N + col;
                if (cF32) ((float*)C)[off] = acc[i][c][r];
                else ((unsigned short*)C)[off] = f2bf(acc[i][c][r]);
            }
}

// ---------------------------------------------------------------------------
// 256x256 double-buffered GEMM (this round). SAME sync structure as gemm_bt
// (stage-next -> frag-read -> MFMA cluster -> vmcnt(0) lgkmcnt(0); barrier),
// scaled so each tile boundary amortizes over 32 MFMA/wave (~1240 cyc/CU of
// matrix work > ~900 cyc HBM latency -> the vmcnt(0) waits on a landed load),
// and the T2 swizzle (now on the critical path) pays.
// 8 waves (2M x 4N), wave tile 128x64. LDS = 2 x (256x32 A + 256x32 B) x 2B
// = 64 KiB static. Per-thread staging: 4 async16 per tile (A-half0, A-half1,
// B-half0, B-half1; halves at +128 rows, swizzle key invariant mod 128).
// bf16 output only (GEMM1).
// ---------------------------------------------------------------------------
__global__ __launch_bounds__(512) void gemm256(
    const unsigned short* __restrict__ A,   // [M][K] bf16
    const unsigned short* __restrict__ BT,  // [N][K] bf16
    unsigned short* __restrict__ Cb,        // [M][N] bf16
    int M, int N, int K)
{
    __shared__ unsigned short As[2][256 * 32];
    __shared__ unsigned short Bs[2][256 * 32];
    const int tid = threadIdx.x;
    const int w = tid >> 6, lane = tid & 63;
    const int quad = lane >> 4, l16 = lane & 15;
    const int wm = w >> 2, wn = w & 3;                 // 2 x 4 wave grid
    const int m0 = blockIdx.y * 256, n0 = blockIdx.x * 256;
    const int nkt = K >> 5;

    // staging: wave w covers rows [w*16, +16) and [w*16+128, +16); lane>>2 =
    // row-in-16, lane&3 = dest chunk. Source chunk inverse-swizzled with key
    // (row>>1)&3 = (lane>>3)&3 (w*16 and +128 contribute 0 to the key).
    const int sRow = w * 16 + (lane >> 2);
    const int sCol = ((lane & 3) ^ ((lane >> 3) & 3)) * 8;
    const unsigned short* aG = A  + (size_t)(m0 + sRow) * K + sCol;
    const unsigned short* bG = BT + (size_t)(n0 + sRow) * K + sCol;
    const int ldsO0 = (w * 16) * 32;
    const int ldsO1 = (w * 16 + 128) * 32;

    // fragment reads: key (row>>1)&3 = (l16>>1)&3 for all i/c/wm/wn
    // (wm*128, wn*64, i*16, c*16 all contribute 0).
    const int kch  = (quad ^ ((l16 >> 1) & 3)) * 8;
    const int aOff = (wm * 128 + l16) * 32 + kch;
    const int bOff = (wn * 64 + l16) * 32 + kch;

    f32x4 acc[8][4] = {};

    // prologue: stage tile 0
    async16(aG, &As[0][ldsO0]);
    async16(aG + (size_t)128 * K, &As[0][ldsO1]);
    async16(bG, &Bs[0][ldsO0]);
    async16(bG + (size_t)128 * K, &Bs[0][ldsO1]);
    asm volatile("s_waitcnt vmcnt(0)\n\ts_barrier" ::: "memory");

    int ct = 0;
    for (int t = 0; t < nkt; ++t) {
        if (t + 1 < nkt) {
            const int k1 = (t + 1) * 32;
            async16(aG + k1, &As[ct ^ 1][ldsO0]);
            async16(aG + (size_t)128 * K + k1, &As[ct ^ 1][ldsO1]);
            async16(bG + k1, &Bs[ct ^ 1][ldsO0]);
            async16(bG + (size_t)128 * K + k1, &Bs[ct ^ 1][ldsO1]);
        }

        bf16x8 af[8], bf[4];
        #pragma unroll
        for (int i = 0; i < 8; i++)
            af[i] = *reinterpret_cast<const bf16x8*>(&As[ct][aOff + i * 16 * 32]);
        #pragma unroll
        for (int c = 0; c < 4; c++)
            bf[c] = *reinterpret_cast<const bf16x8*>(&Bs[ct][bOff + c * 16 * 32]);

        __builtin_amdgcn_s_setprio(1);
        #pragma unroll
        for (int i = 0; i < 8; i++)
            #pragma unroll
            for (int c = 0; c < 4; c++)
                acc[i][c] = __builtin_amdgcn_mfma_f32_16x16x32_bf16(af[i], bf[c], acc[i][c], 0, 0, 0);
        __builtin_amdgcn_s_setprio(0);

        asm volatile("s_waitcnt vmcnt(0) lgkmcnt(0)\n\ts_barrier" ::: "memory");
        ct ^= 1;
    }

    #pragma unroll
    for (int i = 0; i < 8; i++)
        #pragma unroll
        for (int c = 0; c < 4; c++)
            #pragma unroll
            for (int r = 0; r < 4; r++) {
                const int row = m0 + wm * 128 + i * 16 + quad * 4 + r;
                const int col = n0 + wn * 64 + c * 16 + l16;
                Cb[(size_t)row * N + col] = f2bf(acc[i][c][r]);
            }
}

// ---------------------------------------------------------------------------
// Flash attention v2 (causal), swapped-QK^T / lane-local softmax,
// double-buffered K/V staging with counted-vmcnt pipeline (round-2 version,
// unchanged — it measured well).
// ---------------------------------------------------------------------------
__global__ __launch_bounds__(256, 2) void flash_attn(
    const unsigned short* __restrict__ qkv,
    const unsigned short* __restrict__ VT,
    unsigned short* __restrict__ Out)
{
    const int T = 2048, CH = 6144;
    __shared__ unsigned short KsBuf[2][64 * 128];   // [kv][d-chunk swizzled]
    __shared__ unsigned short VtBuf[2][128 * 64];   // [d][kv'-chunk swizzled]

    const int tid = threadIdx.x;
    const int w = tid >> 6, lane = tid & 63;
    const int quad = lane >> 4, l16 = lane & 15;
    const int bh = blockIdx.y, b = bh >> 4, h = bh & 15;
    const int q0 = (gridDim.x - 1 - blockIdx.x) * 128;   // heavy blocks first

    const float sc = 0.08838834764831845f * 1.4426950408889634f;
    const float NINF = -__builtin_inff();

    // Q fragments (B-operand), scale folded in
    bf16x8 qf[2][4];
    #pragma unroll
    for (int st = 0; st < 2; st++) {
        const unsigned short* qrow = qkv + (size_t)(b * T + q0 + w * 32 + st * 16 + l16) * CH + h * 128;
        #pragma unroll
        for (int dc = 0; dc < 4; dc++) {
            u16x8 raw = *reinterpret_cast<const u16x8*>(qrow + dc * 32 + quad * 8);
            u16x8 scl;
            #pragma unroll
            for (int e = 0; e < 8; e++) {
                float f = __builtin_bit_cast(float, (unsigned int)raw[e] << 16);
                scl[e] = f2bf(f * sc);
            }
            qf[st][dc] = __builtin_bit_cast(bf16x8, scl);
        }
    }

    f32x4 o[2][8] = {};
    float m_i[2] = {NINF, NINF};
    float l_i[2] = {0.f, 0.f};
    const int xsw = l16 & 7;

    const int kRow = (lane >> 4);
    const int kCh  = lane & 15;
    const int vRow = (lane >> 3);
    const int vCh  = lane & 7;

    auto stageKV = [&](int kv0, unsigned short* kp, unsigned short* vp) {
        #pragma unroll
        for (int i = 0; i < 4; i++) {
            const int r0 = i * 16 + w * 4;
            const int kv = r0 + kRow;
            const int ch = kCh ^ (kv & 7);
            async16(qkv + (size_t)(b * T + kv0 + kv) * CH + 2048 + h * 128 + ch * 8,
                    kp + r0 * 128);
        }
        #pragma unroll
        for (int i = 0; i < 4; i++) {
            const int r0 = i * 32 + w * 8;
            const int d = r0 + vRow;
            const int ch = vCh ^ (d & 7);
            async16(VT + ((size_t)bh * 128 + d) * T + kv0 + ch * 8,
                    vp + r0 * 64);
        }
    };

    unsigned short* kc = KsBuf[0];
    unsigned short* vc = VtBuf[0];
    unsigned short* kn = KsBuf[1];
    unsigned short* vn = VtBuf[1];

    const int nt = (q0 + 128) / 64;

    stageKV(0, kc, vc);
    asm volatile("s_waitcnt vmcnt(0)\n\ts_barrier" ::: "memory");

    for (int t = 0; t < nt; ++t) {
        const int kv0 = t * 64;
        if (t + 1 < nt) stageKV((t + 1) * 64, kn, vn);

        // ---- S^T = K Q^T ----
        f32x4 s[2][4] = {};
        __builtin_amdgcn_s_setprio(1);
        #pragma unroll
        for (int dc = 0; dc < 4; dc++)
            #pragma unroll
            for (int ntt = 0; ntt < 4; ntt++) {
                bf16x8 kf = *reinterpret_cast<const bf16x8*>(
                    &kc[(ntt * 16 + l16) * 128 + (((dc * 4 + quad) ^ xsw) << 3)]);
                s[0][ntt] = __builtin_amdgcn_mfma_f32_16x16x32_bf16(kf, qf[0][dc], s[0][ntt], 0, 0, 0);
                s[1][ntt] = __builtin_amdgcn_mfma_f32_16x16x32_bf16(kf, qf[1][dc], s[1][ntt], 0, 0, 0);
            }
        __builtin_amdgcn_s_setprio(0);

        // ---- softmax, lane-local rows ----
        unsigned int pk[2][4][2];
        #pragma unroll
        for (int st = 0; st < 2; st++) {
            const int qs = q0 + w * 32 + st * 16;
            const int qrow = qs + l16;
            if (kv0 + 63 > qs) {                     // diagonal: causal mask
                #pragma unroll
                for (int ntt = 0; ntt < 4; ntt++)
                    #pragma unroll
                    for (int r = 0; r < 4; r++)
                        if (kv0 + ntt * 16 + quad * 4 + r > qrow) s[st][ntt][r] = NINF;
            }
            float mx = fmaxf(fmaxf(fmaxf(s[st][0][0], s[st][0][1]), fmaxf(s[st][0][2], s[st][0][3])),
                             fmaxf(fmaxf(s[st][1][0], s[st][1][1]), fmaxf(s[st][1][2], s[st][1][3])));
            mx = fmaxf(mx,
                 fmaxf(fmaxf(fmaxf(s[st][2][0], s[st][2][1]), fmaxf(s[st][2][2], s[st][2][3])),
                       fmaxf(fmaxf(s[st][3][0], s[st][3][1]), fmaxf(s[st][3][2], s[st][3][3]))));
            mx = fmaxf(mx, __shfl_xor(mx, 16));
            mx = fmaxf(mx, __shfl_xor(mx, 32));

            const float mold = m_i[st];
            if (!__all(mx <= mold + 8.0f)) {         // rescale (rare)
                const float mnew = fmaxf(mold, mx);
                const float alpha = exp2f(mold - mnew);
                m_i[st] = mnew;
                l_i[st] *= alpha;
                #pragma unroll
                for (int r = 0; r < 4; r++) {
                    const float a = __shfl(alpha, quad * 4 + r);
                    #pragma unroll
                    for (int c = 0; c < 8; c++) o[st][c][r] *= a;
                }
            }
            const float m = m_i[st];
            float p[4][4];
            #pragma unroll
            for (int ntt = 0; ntt < 4; ntt++)
                #pragma unroll
                for (int r = 0; r < 4; r++)
                    p[ntt][r] = exp2f(s[st][ntt][r] - m);
            float ps = ((p[0][0] + p[0][1]) + (p[0][2] + p[0][3]))
                     + ((p[1][0] + p[1][1]) + (p[1][2] + p[1][3]))
                     + ((p[2][0] + p[2][1]) + (p[2][2] + p[2][3]))
                     + ((p[3][0] + p[3][1]) + (p[3][2] + p[3][3]));
            ps += __shfl_xor(ps, 16);
            ps += __shfl_xor(ps, 32);
            l_i[st] += ps;
            #pragma unroll
            for (int ntt = 0; ntt < 4; ntt++) {
                pk[st][ntt][0] = cvt_pk_bf16(p[ntt][0], p[ntt][1]);
                pk[st][ntt][1] = cvt_pk_bf16(p[ntt][2], p[ntt][3]);
            }
        }

        // ---- O += P V ----
        __builtin_amdgcn_s_setprio(1);
        #pragma unroll
        for (int kc2 = 0; kc2 < 2; kc2++) {
            u32x4 a0, a1;
            a0[0] = pk[0][2*kc2][0];   a0[1] = pk[0][2*kc2][1];
            a0[2] = pk[0][2*kc2+1][0]; a0[3] = pk[0][2*kc2+1][1];
            a1[0] = pk[1][2*kc2][0];   a1[1] = pk[1][2*kc2][1];
            a1[2] = pk[1][2*kc2+1][0]; a1[3] = pk[1][2*kc2+1][1];
            const bf16x8 pf0 = __builtin_bit_cast(bf16x8, a0);
            const bf16x8 pf1 = __builtin_bit_cast(bf16x8, a1);
            #pragma unroll
            for (int c = 0; c < 8; c++) {
                bf16x8 vf = *reinterpret_cast<const bf16x8*>(
                    &vc[(c * 16 + l16) * 64 + (((kc2 * 4 + quad) ^ xsw) << 3)]);
                o[0][c] = __builtin_amdgcn_mfma_f32_16x16x32_bf16(pf0, vf, o[0][c], 0, 0, 0);
                o[1][c] = __builtin_amdgcn_mfma_f32_16x16x32_bf16(pf1, vf, o[1][c], 0, 0, 0);
            }
        }
        __builtin_amdgcn_s_setprio(0);

        asm volatile("s_waitcnt vmcnt(0) lgkmcnt(0)\n\ts_barrier" ::: "memory");

        unsigned short* tp;
        tp = kc; kc = kn; kn = tp;
        tp = vc; vc = vn; vn = tp;
    }

    #pragma unroll
    for (int st = 0; st < 2; st++)
        #pragma unroll
        for (int r = 0; r < 4; r++) {
            const float linv = 1.0f / __shfl(l_i[st], quad * 4 + r);
            const int row = q0 + w * 32 + st * 16 + quad * 4 + r;
            const size_t base = (size_t)(b * T + row) * 2048 + h * 128;
            #pragma unroll
            for (int c = 0; c < 8; c++)
                Out[base + c * 16 + l16] = f2bf(o[st][c][r] * linv);
        }
}

extern "C" void kernel_launch(void* const* d_in, const int* in_sizes, int n_in,
                              void* d_out, int out_size, void* d_ws, size_t ws_size,
                              hipStream_t stream) {
    const int B = 2, T = 2048, C = 2048;
    const float* x    = (const float*)d_in[0];
    const float* Wqkv = (const float*)d_in[2];   // [C][3C] fp32
    const float* Wout = (const float*)d_in[3];   // [C][C]  fp32
    const int M = B * T;                         // 4096

    char* ws = (char*)d_ws;
    unsigned short* qkv   = (unsigned short*)ws;                       // +0
    unsigned short* xb    = (unsigned short*)(ws + 50331648);          // region A
    unsigned short* WoutT = xb;
    unsigned short* WqkvT = (unsigned short*)(ws + 67108864);          // region B
    unsigned short* VTp   = WqkvT;
    unsigned short* O     = (unsigned short*)(ws + 92274688);

    // 1) casts for GEMM1
    cast_bf16<<<dim3(M * C / 8 / 256), 256, 0, stream>>>(x, xb, M * C / 8);
    transpose_cast_f32<<<dim3(3 * C / 64, C / 64), 256, 0, stream>>>(Wqkv, WqkvT, C, 3 * C);
    // 2) qkv = xb @ WqkvT^T  (256x256 tile, 384 blocks)
    gemm256<<<dim3(3 * C / 256, M / 256), 512, 0, stream>>>(xb, WqkvT, qkv, M, 3 * C, C);
    // 3) V transpose (k-permuted layout) and Wout cast
    vtrans<<<dim3(T / 64, 2, B * 16), 256, 0, stream>>>(qkv, VTp);
    transpose_cast_f32<<<dim3(C / 64, C / 64), 256, 0, stream>>>(Wout, WoutT, C, C);
    // 4) flash attention
    flash_attn<<<dim3(T / 128, B * 16), 256, 0, stream>>>(qkv, VTp, O);
    // 5) out = O @ WoutT^T (fp32 out; 512 blocks -> 2/CU shaping kept)
    gemm_bt<<<dim3(C / 128, M / 128), 256, 0, stream>>>(O, WoutT, d_out, M, C, C, 1);
}

// Round 7
// 443.020 us; speedup vs baseline: 1.0413x; 1.0413x over previous
//
#include <hip/hip_runtime.h>
#include <stdint.h>

typedef __bf16 bf16x8 __attribute__((ext_vector_type(8)));
typedef float f32x4 __attribute__((ext_vector_type(4)));
typedef unsigned short u16x8 __attribute__((ext_vector_type(8)));
typedef unsigned int u32x4 __attribute__((ext_vector_type(4)));

__device__ __forceinline__ unsigned short f2bf(float f) {
    unsigned int u = __builtin_bit_cast(unsigned int, f);
    unsigned int r = u + 0x7fffu + ((u >> 16) & 1u);
    return (unsigned short)(r >> 16);
}

// v_cvt_pk_bf16_f32: lo <- bf16(a), hi <- bf16(b)
__device__ __forceinline__ unsigned int cvt_pk_bf16(float a, float b) {
    unsigned int r;
    asm("v_cvt_pk_bf16_f32 %0, %1, %2" : "=v"(r) : "v"(a), "v"(b));
    return r;
}

// async global->LDS, 16B per lane. LDS dest = wave-uniform base + lane*16.
__device__ __forceinline__ void async16(const void* g, void* l) {
    __builtin_amdgcn_global_load_lds(
        (const __attribute__((address_space(1))) void*)g,
        (__attribute__((address_space(3))) void*)l, 16, 0, 0);
}

// ---------------------------------------------------------------------------
// x fp32 -> bf16, elementwise (8 elems/thread)
// ---------------------------------------------------------------------------
__global__ __launch_bounds__(256) void cast_bf16(
    const float* __restrict__ src, unsigned short* __restrict__ dst, int n8)
{
    int i = blockIdx.x * 256 + threadIdx.x;
    if (i >= n8) return;
    const float* f = src + (size_t)i * 8;
    f32x4 a = *reinterpret_cast<const f32x4*>(f);
    f32x4 b = *reinterpret_cast<const f32x4*>(f + 4);
    u16x8 r;
    r[0]=f2bf(a[0]); r[1]=f2bf(a[1]); r[2]=f2bf(a[2]); r[3]=f2bf(a[3]);
    r[4]=f2bf(b[0]); r[5]=f2bf(b[1]); r[6]=f2bf(b[2]); r[7]=f2bf(b[3]);
    *reinterpret_cast<u16x8*>(dst + (size_t)i * 8) = r;
}

// ---------------------------------------------------------------------------
// W fp32 [R][Cc] -> bf16 W^T [Cc][R]. 64x64 tiles, XOR-swizzled LDS
// ---------------------------------------------------------------------------
__global__ __launch_bounds__(256) void transpose_cast_f32(
    const float* __restrict__ src, unsigned short* __restrict__ dst, int R, int Cc)
{
    __shared__ unsigned short St[64 * 64];
    const int tid = threadIdx.x;
    const int r0 = blockIdx.y * 64, c0 = blockIdx.x * 64;
    const int lr  = tid >> 2;          // 0..63
    const int lcb = (tid & 3) * 16;    // 0,16,32,48
    const float* sp = src + (size_t)(r0 + lr) * Cc + c0 + lcb;
    #pragma unroll
    for (int u = 0; u < 4; u++) {
        f32x4 v = *reinterpret_cast<const f32x4*>(sp + 4 * u);
        #pragma unroll
        for (int e = 0; e < 4; e++) {
            int c = lcb + 4 * u + e;
            St[c * 64 + (((lr >> 3) ^ ((c >> 4) & 3)) << 3) + (lr & 7)] = f2bf(v[e]);
        }
    }
    __syncthreads();
    #pragma unroll
    for (int i = 0; i < 2; i++) {
        int ck = tid + 256 * i;
        int c = ck >> 3, ch = ck & 7;
        u16x8 val = *reinterpret_cast<const u16x8*>(&St[c * 64 + ((ch ^ ((c >> 4) & 3)) << 3)]);
        *reinterpret_cast<u16x8*>(dst + (size_t)(c0 + c) * R + r0 + ch * 8) = val;
    }
}

// ---------------------------------------------------------------------------
// V-part of qkv -> VT [b][h][d][t'] with per-32 t-permutation matching the
// swapped-QK^T P layout (see flash_attn).
// ---------------------------------------------------------------------------
__global__ __launch_bounds__(256) void vtrans(
    const unsigned short* __restrict__ qkv, unsigned short* __restrict__ VT)
{
    const int T = 2048, CH = 6144;
    __shared__ unsigned short St[64 * 64];
    const int tid = threadIdx.x;
    const int bh = blockIdx.z;
    const int b = bh >> 4, h = bh & 15;
    const int t0 = blockIdx.x * 64, d0 = blockIdx.y * 64;
    const int lr  = tid >> 2;
    const int lcb = (tid & 3) * 16;
    const unsigned short* sp = qkv + (size_t)(b * T + t0 + lr) * CH + 4096 + h * 128 + d0 + lcb;
    u16x8 v0 = *reinterpret_cast<const u16x8*>(sp);
    u16x8 v1 = *reinterpret_cast<const u16x8*>(sp + 8);
    #pragma unroll
    for (int e = 0; e < 8; e++) {
        int c = lcb + e;
        St[c * 64 + (((lr >> 3) ^ ((c >> 4) & 3)) << 3) + (lr & 7)] = v0[e];
        c = lcb + 8 + e;
        St[c * 64 + (((lr >> 3) ^ ((c >> 4) & 3)) << 3) + (lr & 7)] = v1[e];
    }
    __syncthreads();
    #pragma unroll
    for (int i = 0; i < 2; i++) {
        int ck = tid + 256 * i;
        int d = ck >> 3, ch = ck & 7;
        const int Q = ch & 3, B32 = ch >> 2;
        u16x8 val;
        #pragma unroll
        for (int e = 0; e < 4; e++) {
            int ta = 32 * B32 + 4 * Q + e;        // first half of chunk
            int tb = ta + 16;                     // second half
            val[e]     = St[d * 64 + (((ta >> 3) ^ ((d >> 4) & 3)) << 3) + (ta & 7)];
            val[4 + e] = St[d * 64 + (((tb >> 3) ^ ((d >> 4) & 3)) << 3) + (tb & 7)];
        }
        *reinterpret_cast<u16x8*>(VT + (size_t)(bh * 128 + d0 + d) * T + t0 + ch * 8) = val;
    }
}

// ---------------------------------------------------------------------------
// 128x128 GEMM with 4-buffer LDS RING, prefetch distance 3, counted vmcnt
// (T4 proper). Fragment layout / T2 swizzle / epilogue identical to the
// round-4/5-proven kernel; only buffer count + wait counts changed.
//   prologue: stage tiles 0,1,2 -> bufs 0,1,2 (12 loads/thread outstanding);
//             vmcnt(8) lands tile 0; barrier.
//   iter t  : stage tile t+3 -> buf[(t+3)&3]; frags from buf[t&3]; 16 MFMA;
//             vmcnt(8) retires exactly tile t+1's 4 loads (issued 3 tiles
//             ago, ~1500-2000 cyc of cover -> landed, near-zero stall);
//             lgkmcnt(0) (WAR: buf[t&3] is rewritten by stage t+4 next iter,
//             after this barrier); s_barrier.
//   tail    : vmcnt(4) at t=nkt-3, vmcnt(0) after.
// LDS = 4 bufs x (8KB A + 8KB B) = 64 KiB (size proven on this harness).
// ---------------------------------------------------------------------------
__global__ __launch_bounds__(256) void gemm_bt(
    const unsigned short* __restrict__ A,   // [M][K] bf16
    const unsigned short* __restrict__ BT,  // [N][K] bf16
    void* __restrict__ C, int M, int N, int K, int cF32)
{
    __shared__ unsigned short As[4][128 * 32];
    __shared__ unsigned short Bs[4][128 * 32];
    const int tid = threadIdx.x;
    const int w = tid >> 6, lane = tid & 63;
    const int quad = lane >> 4, l16 = lane & 15;
    const int wm = (w >> 1) * 64, wn = (w & 1) * 64;
    const int m0 = blockIdx.y * 128, n0 = blockIdx.x * 128;

    const int srow = w * 16 + (lane >> 2);
    const int scol = ((lane & 3) ^ ((lane >> 3) & 3)) * 8;   // inverse-swizzled source chunk
    const unsigned short* aG = A  + (size_t)(m0 + srow) * K + scol;
    const unsigned short* bG = BT + (size_t)(n0 + srow) * K + scol;
    const int ldsO = (w * 16) * 32;            // wave-uniform LDS offset

    const int kch = (quad ^ ((l16 >> 1) & 3)) * 8;   // swizzled fragment chunk

    f32x4 acc[4][4] = {};
    const int nkt = K >> 5;                    // 64 for both GEMMs (>= 3)

    // prologue: stage tiles 0,1,2 into bufs 0,1,2
    #pragma unroll
    for (int tt = 0; tt < 3; tt++) {
        const int kk = tt * 32;
        async16(aG + kk, &As[tt][ldsO]);
        async16(aG + (size_t)64 * K + kk, &As[tt][ldsO + 64 * 32]);
        async16(bG + kk, &Bs[tt][ldsO]);
        async16(bG + (size_t)64 * K + kk, &Bs[tt][ldsO + 64 * 32]);
    }
    asm volatile("s_waitcnt vmcnt(8)\n\ts_barrier" ::: "memory");

    for (int t = 0; t < nkt; ++t) {
        // stage tile t+3 (distance-3 prefetch)
        if (t + 3 < nkt) {
            const int bs = (t + 3) & 3;
            const int k3 = (t + 3) * 32;
            async16(aG + k3, &As[bs][ldsO]);
            async16(aG + (size_t)64 * K + k3, &As[bs][ldsO + 64 * 32]);
            async16(bG + k3, &Bs[bs][ldsO]);
            async16(bG + (size_t)64 * K + k3, &Bs[bs][ldsO + 64 * 32]);
        }

        const int bt = t & 3;
        bf16x8 af[4], bf[4];
        #pragma unroll
        for (int i = 0; i < 4; i++)
            af[i] = *reinterpret_cast<const bf16x8*>(&As[bt][(wm + i * 16 + l16) * 32 + kch]);
        #pragma unroll
        for (int c = 0; c < 4; c++)
            bf[c] = *reinterpret_cast<const bf16x8*>(&Bs[bt][(wn + c * 16 + l16) * 32 + kch]);

        __builtin_amdgcn_s_setprio(1);
        #pragma unroll
        for (int i = 0; i < 4; i++)
            #pragma unroll
            for (int c = 0; c < 4; c++)
                acc[i][c] = __builtin_amdgcn_mfma_f32_16x16x32_bf16(af[i], bf[c], acc[i][c], 0, 0, 0);
        __builtin_amdgcn_s_setprio(0);

        // retire exactly tile t+1's loads (counted, never 0 in steady state)
        if (t + 3 < nkt)
            asm volatile("s_waitcnt vmcnt(8) lgkmcnt(0)\n\ts_barrier" ::: "memory");
        else if (t + 2 < nkt)
            asm volatile("s_waitcnt vmcnt(4) lgkmcnt(0)\n\ts_barrier" ::: "memory");
        else
            asm volatile("s_waitcnt vmcnt(0) lgkmcnt(0)\n\ts_barrier" ::: "memory");
    }

    #pragma unroll
    for (int i = 0; i < 4; i++)
        #pragma unroll
        for (int c = 0; c < 4; c++)
            #pragma unroll
            for (int r = 0; r < 4; r++) {
                const int row = m0 + wm + i * 16 + quad * 4 + r;
                const int col = n0 + wn + c * 16 + l16;
                const size_t off = (size_t)row * N + col;
                if (cF32) ((float*)C)[off] = acc[i][c][r];
                else ((unsigned short*)C)[off] = f2bf(acc[i][c][r]);
            }
}

// ---------------------------------------------------------------------------
// Flash attention v2 (causal), swapped-QK^T / lane-local softmax,
// double-buffered K/V staging with counted-vmcnt pipeline (round-2 version,
// unchanged — it measured well).
// ---------------------------------------------------------------------------
__global__ __launch_bounds__(256, 2) void flash_attn(
    const unsigned short* __restrict__ qkv,
    const unsigned short* __restrict__ VT,
    unsigned short* __restrict__ Out)
{
    const int T = 2048, CH = 6144;
    __shared__ unsigned short KsBuf[2][64 * 128];   // [kv][d-chunk swizzled]
    __shared__ unsigned short VtBuf[2][128 * 64];   // [d][kv'-chunk swizzled]

    const int tid = threadIdx.x;
    const int w = tid >> 6, lane = tid & 63;
    const int quad = lane >> 4, l16 = lane & 15;
    const int bh = blockIdx.y, b = bh >> 4, h = bh & 15;
    const int q0 = (gridDim.x - 1 - blockIdx.x) * 128;   // heavy blocks first

    const float sc = 0.08838834764831845f * 1.4426950408889634f;
    const float NINF = -__builtin_inff();

    // Q fragments (B-operand), scale folded in
    bf16x8 qf[2][4];
    #pragma unroll
    for (int st = 0; st < 2; st++) {
        const unsigned short* qrow = qkv + (size_t)(b * T + q0 + w * 32 + st * 16 + l16) * CH + h * 128;
        #pragma unroll
        for (int dc = 0; dc < 4; dc++) {
            u16x8 raw = *reinterpret_cast<const u16x8*>(qrow + dc * 32 + quad * 8);
            u16x8 scl;
            #pragma unroll
            for (int e = 0; e < 8; e++) {
                float f = __builtin_bit_cast(float, (unsigned int)raw[e] << 16);
                scl[e] = f2bf(f * sc);
            }
            qf[st][dc] = __builtin_bit_cast(bf16x8, scl);
        }
    }

    f32x4 o[2][8] = {};
    float m_i[2] = {NINF, NINF};
    float l_i[2] = {0.f, 0.f};
    const int xsw = l16 & 7;

    const int kRow = (lane >> 4);
    const int kCh  = lane & 15;
    const int vRow = (lane >> 3);
    const int vCh  = lane & 7;

    auto stageKV = [&](int kv0, unsigned short* kp, unsigned short* vp) {
        #pragma unroll
        for (int i = 0; i < 4; i++) {
            const int r0 = i * 16 + w * 4;
            const int kv = r0 + kRow;
            const int ch = kCh ^ (kv & 7);
            async16(qkv + (size_t)(b * T + kv0 + kv) * CH + 2048 + h * 128 + ch * 8,
                    kp + r0 * 128);
        }
        #pragma unroll
        for (int i = 0; i < 4; i++) {
            const int r0 = i * 32 + w * 8;
            const int d = r0 + vRow;
            const int ch = vCh ^ (d & 7);
            async16(VT + ((size_t)bh * 128 + d) * T + kv0 + ch * 8,
                    vp + r0 * 64);
        }
    };

    unsigned short* kc = KsBuf[0];
    unsigned short* vc = VtBuf[0];
    unsigned short* kn = KsBuf[1];
    unsigned short* vn = VtBuf[1];

    const int nt = (q0 + 128) / 64;

    stageKV(0, kc, vc);
    asm volatile("s_waitcnt vmcnt(0)\n\ts_barrier" ::: "memory");

    for (int t = 0; t < nt; ++t) {
        const int kv0 = t * 64;
        if (t + 1 < nt) stageKV((t + 1) * 64, kn, vn);

        // ---- S^T = K Q^T ----
        f32x4 s[2][4] = {};
        __builtin_amdgcn_s_setprio(1);
        #pragma unroll
        for (int dc = 0; dc < 4; dc++)
            #pragma unroll
            for (int ntt = 0; ntt < 4; ntt++) {
                bf16x8 kf = *reinterpret_cast<const bf16x8*>(
                    &kc[(ntt * 16 + l16) * 128 + (((dc * 4 + quad) ^ xsw) << 3)]);
                s[0][ntt] = __builtin_amdgcn_mfma_f32_16x16x32_bf16(kf, qf[0][dc], s[0][ntt], 0, 0, 0);
                s[1][ntt] = __builtin_amdgcn_mfma_f32_16x16x32_bf16(kf, qf[1][dc], s[1][ntt], 0, 0, 0);
            }
        __builtin_amdgcn_s_setprio(0);

        // ---- softmax, lane-local rows ----
        unsigned int pk[2][4][2];
        #pragma unroll
        for (int st = 0; st < 2; st++) {
            const int qs = q0 + w * 32 + st * 16;
            const int qrow = qs + l16;
            if (kv0 + 63 > qs) {                     // diagonal: causal mask
                #pragma unroll
                for (int ntt = 0; ntt < 4; ntt++)
                    #pragma unroll
                    for (int r = 0; r < 4; r++)
                        if (kv0 + ntt * 16 + quad * 4 + r > qrow) s[st][ntt][r] = NINF;
            }
            float mx = fmaxf(fmaxf(fmaxf(s[st][0][0], s[st][0][1]), fmaxf(s[st][0][2], s[st][0][3])),
                             fmaxf(fmaxf(s[st][1][0], s[st][1][1]), fmaxf(s[st][1][2], s[st][1][3])));
            mx = fmaxf(mx,
                 fmaxf(fmaxf(fmaxf(s[st][2][0], s[st][2][1]), fmaxf(s[st][2][2], s[st][2][3])),
                       fmaxf(fmaxf(s[st][3][0], s[st][3][1]), fmaxf(s[st][3][2], s[st][3][3]))));
            mx = fmaxf(mx, __shfl_xor(mx, 16));
            mx = fmaxf(mx, __shfl_xor(mx, 32));

            const float mold = m_i[st];
            if (!__all(mx <= mold + 8.0f)) {         // rescale (rare)
                const float mnew = fmaxf(mold, mx);
                const float alpha = exp2f(mold - mnew);
                m_i[st] = mnew;
                l_i[st] *= alpha;
                #pragma unroll
                for (int r = 0; r < 4; r++) {
                    const float a = __shfl(alpha, quad * 4 + r);
                    #pragma unroll
                    for (int c = 0; c < 8; c++) o[st][c][r] *= a;
                }
            }
            const float m = m_i[st];
            float p[4][4];
            #pragma unroll
            for (int ntt = 0; ntt < 4; ntt++)
                #pragma unroll
                for (int r = 0; r < 4; r++)
                    p[ntt][r] = exp2f(s[st][ntt][r] - m);
            float ps = ((p[0][0] + p[0][1]) + (p[0][2] + p[0][3]))
                     + ((p[1][0] + p[1][1]) + (p[1][2] + p[1][3]))
                     + ((p[2][0] + p[2][1]) + (p[2][2] + p[2][3]))
                     + ((p[3][0] + p[3][1]) + (p[3][2] + p[3][3]));
            ps += __shfl_xor(ps, 16);
            ps += __shfl_xor(ps, 32);
            l_i[st] += ps;
            #pragma unroll
            for (int ntt = 0; ntt < 4; ntt++) {
                pk[st][ntt][0] = cvt_pk_bf16(p[ntt][0], p[ntt][1]);
                pk[st][ntt][1] = cvt_pk_bf16(p[ntt][2], p[ntt][3]);
            }
        }

        // ---- O += P V ----
        __builtin_amdgcn_s_setprio(1);
        #pragma unroll
        for (int kc2 = 0; kc2 < 2; kc2++) {
            u32x4 a0, a1;
            a0[0] = pk[0][2*kc2][0];   a0[1] = pk[0][2*kc2][1];
            a0[2] = pk[0][2*kc2+1][0]; a0[3] = pk[0][2*kc2+1][1];
            a1[0] = pk[1][2*kc2][0];   a1[1] = pk[1][2*kc2][1];
            a1[2] = pk[1][2*kc2+1][0]; a1[3] = pk[1][2*kc2+1][1];
            const bf16x8 pf0 = __builtin_bit_cast(bf16x8, a0);
            const bf16x8 pf1 = __builtin_bit_cast(bf16x8, a1);
            #pragma unroll
            for (int c = 0; c < 8; c++) {
                bf16x8 vf = *reinterpret_cast<const bf16x8*>(
                    &vc[(c * 16 + l16) * 64 + (((kc2 * 4 + quad) ^ xsw) << 3)]);
                o[0][c] = __builtin_amdgcn_mfma_f32_16x16x32_bf16(pf0, vf, o[0][c], 0, 0, 0);
                o[1][c] = __builtin_amdgcn_mfma_f32_16x16x32_bf16(pf1, vf, o[1][c], 0, 0, 0);
            }
        }
        __builtin_amdgcn_s_setprio(0);

        asm volatile("s_waitcnt vmcnt(0) lgkmcnt(0)\n\ts_barrier" ::: "memory");

        unsigned short* tp;
        tp = kc; kc = kn; kn = tp;
        tp = vc; vc = vn; vn = tp;
    }

    #pragma unroll
    for (int st = 0; st < 2; st++)
        #pragma unroll
        for (int r = 0; r < 4; r++) {
            const float linv = 1.0f / __shfl(l_i[st], quad * 4 + r);
            const int row = q0 + w * 32 + st * 16 + quad * 4 + r;
            const size_t base = (size_t)(b * T + row) * 2048 + h * 128;
            #pragma unroll
            for (int c = 0; c < 8; c++)
                Out[base + c * 16 + l16] = f2bf(o[st][c][r] * linv);
        }
}

extern "C" void kernel_launch(void* const* d_in, const int* in_sizes, int n_in,
                              void* d_out, int out_size, void* d_ws, size_t ws_size,
                              hipStream_t stream) {
    const int B = 2, T = 2048, C = 2048;
    const float* x    = (const float*)d_in[0];
    const float* Wqkv = (const float*)d_in[2];   // [C][3C] fp32
    const float* Wout = (const float*)d_in[3];   // [C][C]  fp32
    const int M = B * T;                         // 4096

    char* ws = (char*)d_ws;
    unsigned short* qkv   = (unsigned short*)ws;                       // +0
    unsigned short* xb    = (unsigned short*)(ws + 50331648);          // region A
    unsigned short* WoutT = xb;
    unsigned short* WqkvT = (unsigned short*)(ws + 67108864);          // region B
    unsigned short* VTp   = WqkvT;
    unsigned short* O     = (unsigned short*)(ws + 92274688);

    // 1) casts for GEMM1
    cast_bf16<<<dim3(M * C / 8 / 256), 256, 0, stream>>>(x, xb, M * C / 8);
    transpose_cast_f32<<<dim3(3 * C / 64, C / 64), 256, 0, stream>>>(Wqkv, WqkvT, C, 3 * C);
    // 2) qkv = xb @ WqkvT^T  (128^2 ring-pipelined, 1536 blocks)
    gemm_bt<<<dim3(3 * C / 128, M / 128), 256, 0, stream>>>(xb, WqkvT, qkv, M, 3 * C, C, 0);
    // 3) V transpose (k-permuted layout) and Wout cast
    vtrans<<<dim3(T / 64, 2, B * 16), 256, 0, stream>>>(qkv, VTp);
    transpose_cast_f32<<<dim3(C / 64, C / 64), 256, 0, stream>>>(Wout, WoutT, C, C);
    // 4) flash attention
    flash_attn<<<dim3(T / 128, B * 16), 256, 0, stream>>>(qkv, VTp, O);
    // 5) out = O @ WoutT^T (fp32 out, 512 blocks)
    gemm_bt<<<dim3(C / 128, M / 128), 256, 0, stream>>>(O, WoutT, d_out, M, C, C, 1);
}

// Round 8
// 416.576 us; speedup vs baseline: 1.1074x; 1.0635x over previous
//
#include <hip/hip_runtime.h>
#include <stdint.h>

typedef __bf16 bf16x8 __attribute__((ext_vector_type(8)));
typedef float f32x4 __attribute__((ext_vector_type(4)));
typedef unsigned short u16x8 __attribute__((ext_vector_type(8)));
typedef unsigned int u32x4 __attribute__((ext_vector_type(4)));

__device__ __forceinline__ unsigned short f2bf(float f) {
    unsigned int u = __builtin_bit_cast(unsigned int, f);
    unsigned int r = u + 0x7fffu + ((u >> 16) & 1u);
    return (unsigned short)(r >> 16);
}

// v_cvt_pk_bf16_f32: lo <- bf16(a), hi <- bf16(b)
__device__ __forceinline__ unsigned int cvt_pk_bf16(float a, float b) {
    unsigned int r;
    asm("v_cvt_pk_bf16_f32 %0, %1, %2" : "=v"(r) : "v"(a), "v"(b));
    return r;
}

// async global->LDS, 16B per lane. LDS dest = wave-uniform base + lane*16.
__device__ __forceinline__ void async16(const void* g, void* l) {
    __builtin_amdgcn_global_load_lds(
        (const __attribute__((address_space(1))) void*)g,
        (__attribute__((address_space(3))) void*)l, 16, 0, 0);
}

// ---------------------------------------------------------------------------
// Bodies for the fused prep kernels (block-granular branching, no intra-block
// divergence; each body uses <=8KB of the shared St buffer and 256 threads).
// ---------------------------------------------------------------------------

// x fp32 -> bf16, 8 elems/thread at flat index i
__device__ __forceinline__ void cast_body(
    const float* __restrict__ src, unsigned short* __restrict__ dst, int i)
{
    const float* f = src + (size_t)i * 8;
    f32x4 a = *reinterpret_cast<const f32x4*>(f);
    f32x4 b = *reinterpret_cast<const f32x4*>(f + 4);
    u16x8 r;
    r[0]=f2bf(a[0]); r[1]=f2bf(a[1]); r[2]=f2bf(a[2]); r[3]=f2bf(a[3]);
    r[4]=f2bf(b[0]); r[5]=f2bf(b[1]); r[6]=f2bf(b[2]); r[7]=f2bf(b[3]);
    *reinterpret_cast<u16x8*>(dst + (size_t)i * 8) = r;
}

// W fp32 [R][Cc] -> bf16 W^T [Cc][R], one 64x64 tile at (bx,by), XOR-swizzled LDS
__device__ __forceinline__ void tcast_body(
    const float* __restrict__ src, unsigned short* __restrict__ dst,
    int R, int Cc, int bx, int by, int tid, unsigned short* St)
{
    const int r0 = by * 64, c0 = bx * 64;
    const int lr  = tid >> 2;          // 0..63
    const int lcb = (tid & 3) * 16;    // 0,16,32,48
    const float* sp = src + (size_t)(r0 + lr) * Cc + c0 + lcb;
    #pragma unroll
    for (int u = 0; u < 4; u++) {
        f32x4 v = *reinterpret_cast<const f32x4*>(sp + 4 * u);
        #pragma unroll
        for (int e = 0; e < 4; e++) {
            int c = lcb + 4 * u + e;
            St[c * 64 + (((lr >> 3) ^ ((c >> 4) & 3)) << 3) + (lr & 7)] = f2bf(v[e]);
        }
    }
    __syncthreads();
    #pragma unroll
    for (int i = 0; i < 2; i++) {
        int ck = tid + 256 * i;
        int c = ck >> 3, ch = ck & 7;
        u16x8 val = *reinterpret_cast<const u16x8*>(&St[c * 64 + ((ch ^ ((c >> 4) & 3)) << 3)]);
        *reinterpret_cast<u16x8*>(dst + (size_t)(c0 + c) * R + r0 + ch * 8) = val;
    }
}

// V-part of qkv -> VT [b][h][d][t'] with per-32 t-permutation matching the
// swapped-QK^T P layout (see flash_attn). One 64x64 tile at (tx, dy, bh).
__device__ __forceinline__ void vtrans_body(
    const unsigned short* __restrict__ qkv, unsigned short* __restrict__ VT,
    int tx, int dy, int bh, int tid, unsigned short* St)
{
    const int T = 2048, CH = 6144;
    const int b = bh >> 4, h = bh & 15;
    const int t0 = tx * 64, d0 = dy * 64;
    const int lr  = tid >> 2;
    const int lcb = (tid & 3) * 16;
    const unsigned short* sp = qkv + (size_t)(b * T + t0 + lr) * CH + 4096 + h * 128 + d0 + lcb;
    u16x8 v0 = *reinterpret_cast<const u16x8*>(sp);
    u16x8 v1 = *reinterpret_cast<const u16x8*>(sp + 8);
    #pragma unroll
    for (int e = 0; e < 8; e++) {
        int c = lcb + e;
        St[c * 64 + (((lr >> 3) ^ ((c >> 4) & 3)) << 3) + (lr & 7)] = v0[e];
        c = lcb + 8 + e;
        St[c * 64 + (((lr >> 3) ^ ((c >> 4) & 3)) << 3) + (lr & 7)] = v1[e];
    }
    __syncthreads();
    #pragma unroll
    for (int i = 0; i < 2; i++) {
        int ck = tid + 256 * i;
        int d = ck >> 3, ch = ck & 7;
        const int Q = ch & 3, B32 = ch >> 2;
        u16x8 val;
        #pragma unroll
        for (int e = 0; e < 4; e++) {
            int ta = 32 * B32 + 4 * Q + e;        // first half of chunk
            int tb = ta + 16;                     // second half
            val[e]     = St[d * 64 + (((ta >> 3) ^ ((d >> 4) & 3)) << 3) + (ta & 7)];
            val[4 + e] = St[d * 64 + (((tb >> 3) ^ ((d >> 4) & 3)) << 3) + (tb & 7)];
        }
        *reinterpret_cast<u16x8*>(VT + (size_t)(bh * 128 + d0 + d) * T + t0 + ch * 8) = val;
    }
}

// ---------------------------------------------------------------------------
// prep1 = cast_bf16(x) UNION transpose_cast(Wqkv). Independent work, fused to
// cut one launch gap and fill CUs concurrently.
//   blocks [0,4096)       : cast, i = bid*256+tid   (n8 = M*C/8 = 1048576)
//   blocks [4096, 7168)   : Wqkv transpose, b2=(bid-4096) -> (b2%96, b2/96)
// ---------------------------------------------------------------------------
__global__ __launch_bounds__(256) void prep1(
    const float* __restrict__ x, unsigned short* __restrict__ xb,
    const float* __restrict__ Wqkv, unsigned short* __restrict__ WqkvT)
{
    __shared__ unsigned short St[64 * 64];
    const int bid = blockIdx.x, tid = threadIdx.x;
    if (bid < 4096) {
        cast_body(x, xb, bid * 256 + tid);
    } else {
        const int b2 = bid - 4096;
        tcast_body(Wqkv, WqkvT, 2048, 6144, b2 % 96, b2 / 96, tid, St);
    }
}

// ---------------------------------------------------------------------------
// prep2 = vtrans(qkv) UNION transpose_cast(Wout). (Wout's dest aliases xb, so
// this must run after GEMM1 — both components do.)
//   blocks [0,2048)       : vtrans, (bid%32, (bid/32)&1, bid/64)
//   blocks [2048, 3072)   : Wout transpose, b2=(bid-2048) -> (b2%32, b2/32)
// ---------------------------------------------------------------------------
__global__ __launch_bounds__(256) void prep2(
    const unsigned short* __restrict__ qkv, unsigned short* __restrict__ VT,
    const float* __restrict__ Wout, unsigned short* __restrict__ WoutT)
{
    __shared__ unsigned short St[64 * 64];
    const int bid = blockIdx.x, tid = threadIdx.x;
    if (bid < 2048) {
        vtrans_body(qkv, VT, bid % 32, (bid >> 5) & 1, bid >> 6, tid, St);
    } else {
        const int b2 = bid - 2048;
        tcast_body(Wout, WoutT, 2048, 2048, b2 % 32, b2 / 32, tid, St);
    }
}

// ---------------------------------------------------------------------------
// 128x128 double-buffered GEMM, single-barrier counted pipeline + T2 swizzle
// (rounds 4+5, PROVEN 133us / 775 TF — the 64KB ring (r7) and 256^2-2ph (r6)
// both regressed via occupancy; this structure's inter-block overlap is the
// latency hiding, per m114/m132).
// ---------------------------------------------------------------------------
__global__ __launch_bounds__(256) void gemm_bt(
    const unsigned short* __restrict__ A,   // [M][K] bf16
    const unsigned short* __restrict__ BT,  // [N][K] bf16
    void* __restrict__ C, int M, int N, int K, int cF32)
{
    __shared__ unsigned short As[2][128 * 32];
    __shared__ unsigned short Bs[2][128 * 32];
    const int tid = threadIdx.x;
    const int w = tid >> 6, lane = tid & 63;
    const int quad = lane >> 4, l16 = lane & 15;
    const int wm = (w >> 1) * 64, wn = (w & 1) * 64;
    const int m0 = blockIdx.y * 128, n0 = blockIdx.x * 128;

    const int srow = w * 16 + (lane >> 2);
    const int scol = ((lane & 3) ^ ((lane >> 3) & 3)) * 8;   // inverse-swizzled source chunk
    const unsigned short* aG = A  + (size_t)(m0 + srow) * K + scol;
    const unsigned short* bG = BT + (size_t)(n0 + srow) * K + scol;
    const int ldsO = (w * 16) * 32;            // wave-uniform LDS offset

    const int kch = (quad ^ ((l16 >> 1) & 3)) * 8;   // swizzled fragment chunk

    f32x4 acc[4][4] = {};
    const int nkt = K >> 5;

    async16(aG, &As[0][ldsO]);
    async16(aG + (size_t)64 * K, &As[0][ldsO + 64 * 32]);
    async16(bG, &Bs[0][ldsO]);
    async16(bG + (size_t)64 * K, &Bs[0][ldsO + 64 * 32]);
    asm volatile("s_waitcnt vmcnt(0)\n\ts_barrier" ::: "memory");

    int ct = 0;
    for (int t = 0; t < nkt; ++t) {
        if (t + 1 < nkt) {
            const int k1 = (t + 1) * 32;
            async16(aG + k1, &As[ct ^ 1][ldsO]);
            async16(aG + (size_t)64 * K + k1, &As[ct ^ 1][ldsO + 64 * 32]);
            async16(bG + k1, &Bs[ct ^ 1][ldsO]);
            async16(bG + (size_t)64 * K + k1, &Bs[ct ^ 1][ldsO + 64 * 32]);
        }

        bf16x8 af[4], bf[4];
        #pragma unroll
        for (int i = 0; i < 4; i++)
            af[i] = *reinterpret_cast<const bf16x8*>(&As[ct][(wm + i * 16 + l16) * 32 + kch]);
        #pragma unroll
        for (int c = 0; c < 4; c++)
            bf[c] = *reinterpret_cast<const bf16x8*>(&Bs[ct][(wn + c * 16 + l16) * 32 + kch]);

        __builtin_amdgcn_s_setprio(1);
        #pragma unroll
        for (int i = 0; i < 4; i++)
            #pragma unroll
            for (int c = 0; c < 4; c++)
                acc[i][c] = __builtin_amdgcn_mfma_f32_16x16x32_bf16(af[i], bf[c], acc[i][c], 0, 0, 0);
        __builtin_amdgcn_s_setprio(0);

        asm volatile("s_waitcnt vmcnt(0) lgkmcnt(0)\n\ts_barrier" ::: "memory");
        ct ^= 1;
    }

    #pragma unroll
    for (int i = 0; i < 4; i++)
        #pragma unroll
        for (int c = 0; c < 4; c++)
            #pragma unroll
            for (int r = 0; r < 4; r++) {
                const int row = m0 + wm + i * 16 + quad * 4 + r;
                const int col = n0 + wn + c * 16 + l16;
                const size_t off = (size_t)row * N + col;
                if (cF32) ((float*)C)[off] = acc[i][c][r];
                else ((unsigned short*)C)[off] = f2bf(acc[i][c][r]);
            }
}

// ---------------------------------------------------------------------------
// Flash attention v2 (causal), swapped-QK^T / lane-local softmax,
// double-buffered K/V staging with counted-vmcnt pipeline (round-2 version,
// unchanged — it measured well).
// ---------------------------------------------------------------------------
__global__ __launch_bounds__(256, 2) void flash_attn(
    const unsigned short* __restrict__ qkv,
    const unsigned short* __restrict__ VT,
    unsigned short* __restrict__ Out)
{
    const int T = 2048, CH = 6144;
    __shared__ unsigned short KsBuf[2][64 * 128];   // [kv][d-chunk swizzled]
    __shared__ unsigned short VtBuf[2][128 * 64];   // [d][kv'-chunk swizzled]

    const int tid = threadIdx.x;
    const int w = tid >> 6, lane = tid & 63;
    const int quad = lane >> 4, l16 = lane & 15;
    const int bh = blockIdx.y, b = bh >> 4, h = bh & 15;
    const int q0 = (gridDim.x - 1 - blockIdx.x) * 128;   // heavy blocks first

    const float sc = 0.08838834764831845f * 1.4426950408889634f;
    const float NINF = -__builtin_inff();

    // Q fragments (B-operand), scale folded in
    bf16x8 qf[2][4];
    #pragma unroll
    for (int st = 0; st < 2; st++) {
        const unsigned short* qrow = qkv + (size_t)(b * T + q0 + w * 32 + st * 16 + l16) * CH + h * 128;
        #pragma unroll
        for (int dc = 0; dc < 4; dc++) {
            u16x8 raw = *reinterpret_cast<const u16x8*>(qrow + dc * 32 + quad * 8);
            u16x8 scl;
            #pragma unroll
            for (int e = 0; e < 8; e++) {
                float f = __builtin_bit_cast(float, (unsigned int)raw[e] << 16);
                scl[e] = f2bf(f * sc);
            }
            qf[st][dc] = __builtin_bit_cast(bf16x8, scl);
        }
    }

    f32x4 o[2][8] = {};
    float m_i[2] = {NINF, NINF};
    float l_i[2] = {0.f, 0.f};
    const int xsw = l16 & 7;

    const int kRow = (lane >> 4);
    const int kCh  = lane & 15;
    const int vRow = (lane >> 3);
    const int vCh  = lane & 7;

    auto stageKV = [&](int kv0, unsigned short* kp, unsigned short* vp) {
        #pragma unroll
        for (int i = 0; i < 4; i++) {
            const int r0 = i * 16 + w * 4;
            const int kv = r0 + kRow;
            const int ch = kCh ^ (kv & 7);
            async16(qkv + (size_t)(b * T + kv0 + kv) * CH + 2048 + h * 128 + ch * 8,
                    kp + r0 * 128);
        }
        #pragma unroll
        for (int i = 0; i < 4; i++) {
            const int r0 = i * 32 + w * 8;
            const int d = r0 + vRow;
            const int ch = vCh ^ (d & 7);
            async16(VT + ((size_t)bh * 128 + d) * T + kv0 + ch * 8,
                    vp + r0 * 64);
        }
    };

    unsigned short* kc = KsBuf[0];
    unsigned short* vc = VtBuf[0];
    unsigned short* kn = KsBuf[1];
    unsigned short* vn = VtBuf[1];

    const int nt = (q0 + 128) / 64;

    stageKV(0, kc, vc);
    asm volatile("s_waitcnt vmcnt(0)\n\ts_barrier" ::: "memory");

    for (int t = 0; t < nt; ++t) {
        const int kv0 = t * 64;
        if (t + 1 < nt) stageKV((t + 1) * 64, kn, vn);

        // ---- S^T = K Q^T ----
        f32x4 s[2][4] = {};
        __builtin_amdgcn_s_setprio(1);
        #pragma unroll
        for (int dc = 0; dc < 4; dc++)
            #pragma unroll
            for (int ntt = 0; ntt < 4; ntt++) {
                bf16x8 kf = *reinterpret_cast<const bf16x8*>(
                    &kc[(ntt * 16 + l16) * 128 + (((dc * 4 + quad) ^ xsw) << 3)]);
                s[0][ntt] = __builtin_amdgcn_mfma_f32_16x16x32_bf16(kf, qf[0][dc], s[0][ntt], 0, 0, 0);
                s[1][ntt] = __builtin_amdgcn_mfma_f32_16x16x32_bf16(kf, qf[1][dc], s[1][ntt], 0, 0, 0);
            }
        __builtin_amdgcn_s_setprio(0);

        // ---- softmax, lane-local rows ----
        unsigned int pk[2][4][2];
        #pragma unroll
        for (int st = 0; st < 2; st++) {
            const int qs = q0 + w * 32 + st * 16;
            const int qrow = qs + l16;
            if (kv0 + 63 > qs) {                     // diagonal: causal mask
                #pragma unroll
                for (int ntt = 0; ntt < 4; ntt++)
                    #pragma unroll
                    for (int r = 0; r < 4; r++)
                        if (kv0 + ntt * 16 + quad * 4 + r > qrow) s[st][ntt][r] = NINF;
            }
            float mx = fmaxf(fmaxf(fmaxf(s[st][0][0], s[st][0][1]), fmaxf(s[st][0][2], s[st][0][3])),
                             fmaxf(fmaxf(s[st][1][0], s[st][1][1]), fmaxf(s[st][1][2], s[st][1][3])));
            mx = fmaxf(mx,
                 fmaxf(fmaxf(fmaxf(s[st][2][0], s[st][2][1]), fmaxf(s[st][2][2], s[st][2][3])),
                       fmaxf(fmaxf(s[st][3][0], s[st][3][1]), fmaxf(s[st][3][2], s[st][3][3]))));
            mx = fmaxf(mx, __shfl_xor(mx, 16));
            mx = fmaxf(mx, __shfl_xor(mx, 32));

            const float mold = m_i[st];
            if (!__all(mx <= mold + 8.0f)) {         // rescale (rare)
                const float mnew = fmaxf(mold, mx);
                const float alpha = exp2f(mold - mnew);
                m_i[st] = mnew;
                l_i[st] *= alpha;
                #pragma unroll
                for (int r = 0; r < 4; r++) {
                    const float a = __shfl(alpha, quad * 4 + r);
                    #pragma unroll
                    for (int c = 0; c < 8; c++) o[st][c][r] *= a;
                }
            }
            const float m = m_i[st];
            float p[4][4];
            #pragma unroll
            for (int ntt = 0; ntt < 4; ntt++)
                #pragma unroll
                for (int r = 0; r < 4; r++)
                    p[ntt][r] = exp2f(s[st][ntt][r] - m);
            float ps = ((p[0][0] + p[0][1]) + (p[0][2] + p[0][3]))
                     + ((p[1][0] + p[1][1]) + (p[1][2] + p[1][3]))
                     + ((p[2][0] + p[2][1]) + (p[2][2] + p[2][3]))
                     + ((p[3][0] + p[3][1]) + (p[3][2] + p[3][3]));
            ps += __shfl_xor(ps, 16);
            ps += __shfl_xor(ps, 32);
            l_i[st] += ps;
            #pragma unroll
            for (int ntt = 0; ntt < 4; ntt++) {
                pk[st][ntt][0] = cvt_pk_bf16(p[ntt][0], p[ntt][1]);
                pk[st][ntt][1] = cvt_pk_bf16(p[ntt][2], p[ntt][3]);
            }
        }

        // ---- O += P V ----
        __builtin_amdgcn_s_setprio(1);
        #pragma unroll
        for (int kc2 = 0; kc2 < 2; kc2++) {
            u32x4 a0, a1;
            a0[0] = pk[0][2*kc2][0];   a0[1] = pk[0][2*kc2][1];
            a0[2] = pk[0][2*kc2+1][0]; a0[3] = pk[0][2*kc2+1][1];
            a1[0] = pk[1][2*kc2][0];   a1[1] = pk[1][2*kc2][1];
            a1[2] = pk[1][2*kc2+1][0]; a1[3] = pk[1][2*kc2+1][1];
            const bf16x8 pf0 = __builtin_bit_cast(bf16x8, a0);
            const bf16x8 pf1 = __builtin_bit_cast(bf16x8, a1);
            #pragma unroll
            for (int c = 0; c < 8; c++) {
                bf16x8 vf = *reinterpret_cast<const bf16x8*>(
                    &vc[(c * 16 + l16) * 64 + (((kc2 * 4 + quad) ^ xsw) << 3)]);
                o[0][c] = __builtin_amdgcn_mfma_f32_16x16x32_bf16(pf0, vf, o[0][c], 0, 0, 0);
                o[1][c] = __builtin_amdgcn_mfma_f32_16x16x32_bf16(pf1, vf, o[1][c], 0, 0, 0);
            }
        }
        __builtin_amdgcn_s_setprio(0);

        asm volatile("s_waitcnt vmcnt(0) lgkmcnt(0)\n\ts_barrier" ::: "memory");

        unsigned short* tp;
        tp = kc; kc = kn; kn = tp;
        tp = vc; vc = vn; vn = tp;
    }

    #pragma unroll
    for (int st = 0; st < 2; st++)
        #pragma unroll
        for (int r = 0; r < 4; r++) {
            const float linv = 1.0f / __shfl(l_i[st], quad * 4 + r);
            const int row = q0 + w * 32 + st * 16 + quad * 4 + r;
            const size_t base = (size_t)(b * T + row) * 2048 + h * 128;
            #pragma unroll
            for (int c = 0; c < 8; c++)
                Out[base + c * 16 + l16] = f2bf(o[st][c][r] * linv);
        }
}

extern "C" void kernel_launch(void* const* d_in, const int* in_sizes, int n_in,
                              void* d_out, int out_size, void* d_ws, size_t ws_size,
                              hipStream_t stream) {
    const int B = 2, T = 2048, C = 2048;
    const float* x    = (const float*)d_in[0];
    const float* Wqkv = (const float*)d_in[2];   // [C][3C] fp32
    const float* Wout = (const float*)d_in[3];   // [C][C]  fp32
    const int M = B * T;                         // 4096

    char* ws = (char*)d_ws;
    unsigned short* qkv   = (unsigned short*)ws;                       // +0
    unsigned short* xb    = (unsigned short*)(ws + 50331648);          // region A
    unsigned short* WoutT = xb;
    unsigned short* WqkvT = (unsigned short*)(ws + 67108864);          // region B
    unsigned short* VTp   = WqkvT;
    unsigned short* O     = (unsigned short*)(ws + 92274688);

    // 1) prep1: x->bf16 cast (4096 blocks) + Wqkv transpose-cast (3072 blocks)
    prep1<<<dim3(4096 + 3072), 256, 0, stream>>>(x, xb, Wqkv, WqkvT);
    // 2) qkv = xb @ WqkvT^T
    gemm_bt<<<dim3(3 * C / 128, M / 128), 256, 0, stream>>>(xb, WqkvT, qkv, M, 3 * C, C, 0);
    // 3) prep2: V transpose (2048 blocks) + Wout transpose-cast (1024 blocks)
    //    (Wout's dest aliases xb -> must be after GEMM1)
    prep2<<<dim3(2048 + 1024), 256, 0, stream>>>(qkv, VTp, Wout, WoutT);
    // 4) flash attention
    flash_attn<<<dim3(T / 128, B * 16), 256, 0, stream>>>(qkv, VTp, O);
    // 5) out = O @ WoutT^T (fp32 out)
    gemm_bt<<<dim3(C / 128, M / 128), 256, 0, stream>>>(O, WoutT, d_out, M, C, C, 1);
}